// Round 6
// baseline (234.232 us; speedup 1.0000x reference)
//
#include <hip/hip_runtime.h>

namespace {

constexpr int B  = 8;
constexpr int L  = 4096;
constexpr int D  = 1024;
constexpr int D4 = D / 4;        // 256 float4 per row
constexpr int P  = L / 2;        // 2048 pair-rows
constexpr int TJ = 64;           // columns per block (256 B row slice)
constexpr int TP = 32;           // output pairs per block
constexpr int RP = TP + TJ;      // 96 staged pair-rows (3x read redundancy, LLC-absorbed)
constexpr int RR = 2 * RP;       // 192 staged RAW rows
constexpr int NT = 512;          // 8 waves
constexpr int NW = NT / 64;
constexpr int NCH = RR * TJ * 4 / 1024;  // 48 x 1KiB DMA chunks (4 raw rows each)
constexpr int CPW = NCH / NW;            // 6 chunks per wave
static_assert(CPW == 6, "chunk math");
static_assert(RR * TJ * 4 == 48 * 1024, "LDS = 48 KiB, 3 blocks/CU");

typedef float floatx4 __attribute__((ext_vector_type(4)));  // native vec for nt-store

// Async 16B global->LDS DMA. LDS dest is wave-uniform base + lane*16 (linear).
__device__ __forceinline__ void async_ld16(const float* g, float* l) {
  __builtin_amdgcn_global_load_lds(
      (const __attribute__((address_space(1))) void*)g,
      (__attribute__((address_space(3))) void*)l, 16, 0, 0);
}

// out[b, 2p+t, j] = {min,max}(v[b,2q,j], v[b,2q+1,j]), q = (p - h_j) mod P,
// h_j = j-1 (h_0 = 0). 256 B row slices staged raw in LDS (one tile, 2-phase);
// pair min/max fold and the 1-pair-per-column shear resolve at drain.
// Output stores are NON-TEMPORAL: bypass LLC so (a) writes reach the DRAM
// controller in issue order (page-local) instead of LRU-eviction order, and
// (b) the input stays LLC-resident across dispatches (FETCH -> ~0).
__global__ __launch_bounds__(NT, 6)
void swd_kernel(const float* __restrict__ v, float* __restrict__ out) {
  const int j0 = blockIdx.x * TJ;
  const int p0 = blockIdx.y * TP;
  const int b  = blockIdx.z;

  __shared__ float lds[RR * TJ];   // raw row r lives at [r*TJ, r*TJ+TJ)

  const int tid  = threadIdx.x;
  const int wave = tid >> 6;
  const int lane = tid & 63;

  const float* __restrict__ vb = v + (size_t)b * L * D + j0;
  const int r0 = p0 - (j0 + TJ - 2);     // lowest staged pair index (mod P)

  // ---- Stage: chunk C = wave + NW*i covers raw rows 4C..4C+3 (256 B slices)
  const int f  = lane & 15;              // 16 B quad within 256 B row slice
  const int rc = lane >> 4;              // raw row within chunk
#pragma unroll
  for (int i = 0; i < CPW; ++i) {
    const int C   = wave + NW * i;       // 1 KiB chunk index, wave-uniform
    const int kr  = 4 * C + rc;          // raw staged row 0..191
    const int q   = (r0 + (kr >> 1)) & (P - 1);
    const int row = 2 * q + (kr & 1);
    async_ld16(vb + (size_t)row * D + 4 * f, &lds[C * 256]);
  }
  asm volatile("s_waitcnt vmcnt(0)" ::: "memory");
  __syncthreads();

  // ---- Drain: thread owns column quad g (0..15), output pair c (0..31).
  const int g = tid & 15;
  const int c = tid >> 4;
  // pair-row (window index) for component x: K0 = c + (TJ-1) - 4g;
  // components x,y,z,w use pairs K0, K0-1, K0-2, K0-3 -> raw rows krb..krb+7.
  const int krb = 2 * c - 8 * g + 2 * (TJ - 1) - 6;   // in [0, 182]
  const bool sp = (j0 == 0) && (g == 0);  // column 0: h_0 = 0, not -1

  float4 m[4], M[4];
#pragma unroll
  for (int u = 0; u < 4; ++u) {
    const float4 a0 = *(const float4*)&lds[(krb + 2 * u)     * TJ + 4 * g];
    const float4 a1 = *(const float4*)&lds[(krb + 2 * u + 1) * TJ + 4 * g];
    m[u].x = fminf(a0.x, a1.x); M[u].x = fmaxf(a0.x, a1.x);
    m[u].y = fminf(a0.y, a1.y); M[u].y = fmaxf(a0.y, a1.y);
    m[u].z = fminf(a0.z, a1.z); M[u].z = fmaxf(a0.z, a1.z);
    m[u].w = fminf(a0.w, a1.w); M[u].w = fmaxf(a0.w, a1.w);
  }

  floatx4 e, o;
  e.x = sp ? m[2].x : m[3].x; e.y = m[2].y; e.z = m[1].z; e.w = m[0].w;
  o.x = sp ? M[2].x : M[3].x; o.y = M[2].y; o.z = M[1].z; o.w = M[0].w;

  float* __restrict__ ob = out + (size_t)b * L * D + j0 + 4 * g;
  const size_t ro = (size_t)(2 * (p0 + c)) * D;
  __builtin_nontemporal_store(e, (floatx4*)(ob + ro));      // row 2p
  __builtin_nontemporal_store(o, (floatx4*)(ob + ro + D));  // row 2p+1
}

} // namespace

extern "C" void kernel_launch(void* const* d_in, const int* /*in_sizes*/, int /*n_in*/,
                              void* d_out, int /*out_size*/, void* /*d_ws*/, size_t /*ws_size*/,
                              hipStream_t stream) {
  const float* v = (const float*)d_in[0];
  float* out = (float*)d_out;
  dim3 grid(D / TJ, P / TP, B);   // (16, 64, 8) = 8192 blocks
  swd_kernel<<<grid, NT, 0, stream>>>(v, out);
}